// Round 8
// baseline (6084.507 us; speedup 1.0000x reference)
//
#include <hip/hip_runtime.h>
#include <hip/hip_bf16.h>
#include <type_traits>

#define NE 8
#define DIN 1024
#define DHID 4096
#define DOUTD 1024
#define NTOK 32768
#define CAP (NTOK / NE)  // 4096 tokens per expert

typedef unsigned short u16;
typedef __attribute__((ext_vector_type(8))) short bf16x8;   // 8 bf16 = 4 VGPR
typedef __attribute__((ext_vector_type(4))) float f32x4;

template <int I> using ic = std::integral_constant<int, I>;

__device__ __forceinline__ u16 f2bf(float x) {
  unsigned u = __builtin_bit_cast(unsigned, x);
  u += 0x7fffu + ((u >> 16) & 1u);   // RNE; finite normals
  return (u16)(u >> 16);
}

// tanh-form GELU (max dev from erf-form ~3e-4; threshold headroom ~4.6x; R4-R6-verified)
__device__ __forceinline__ float gelu_f(float x) {
  float u = 0.7978845608028654f * x * (1.0f + 0.044715f * x * x);
  float t = __expf(-2.0f * fabsf(u));
  float r = __fdividef(2.0f * t, 1.0f + t);   // 1 - tanh|u|
  float th = copysignf(1.0f - r, u);
  return 0.5f * x * (1.0f + th);
}

__device__ __forceinline__ void async_ld16(const void* g, void* l) {
  __builtin_amdgcn_global_load_lds(
      (const __attribute__((address_space(1))) unsigned int*)g,
      (__attribute__((address_space(3))) unsigned int*)l, 16, 0, 0);
}

// ---------------- fp32 -> bf16, 8 elems/thread ----------------
__global__ __launch_bounds__(256) void convert_bf16_kernel(const float* __restrict__ in,
                                                           u16* __restrict__ out) {
  size_t i = ((size_t)blockIdx.x * 256 + threadIdx.x) * 8;
  float4 a = *(const float4*)(in + i);
  float4 b = *(const float4*)(in + i + 4);
  uint4 o;
  o.x = (unsigned)f2bf(a.x) | ((unsigned)f2bf(a.y) << 16);
  o.y = (unsigned)f2bf(a.z) | ((unsigned)f2bf(a.w) << 16);
  o.z = (unsigned)f2bf(b.x) | ((unsigned)f2bf(b.y) << 16);
  o.w = (unsigned)f2bf(b.z) | ((unsigned)f2bf(b.w) << 16);
  *(uint4*)(out + i) = o;
}

// ------------- [E][K][N] fp32 -> [E][N][K] bf16 (64x64 LDS-tiled) -------------
__global__ __launch_bounds__(256) void transpose_bf16_kernel(const float* __restrict__ in,
                                                             u16* __restrict__ out,
                                                             int K, int N) {
  __shared__ __align__(16) u16 tile[64 * 72];
  const int e = blockIdx.z;
  const int n0 = blockIdx.x * 64;
  const int k0 = blockIdx.y * 64;
  const float* inp = in + (size_t)e * K * N;
  u16* outp = out + (size_t)e * N * K;
  const int t = threadIdx.x;
  const int kr = t >> 4;
  const int nc = (t & 15) * 4;
#pragma unroll
  for (int rr = 0; rr < 4; ++rr) {
    int kl = rr * 16 + kr;
    float4 v = *(const float4*)(inp + (size_t)(k0 + kl) * N + n0 + nc);
    tile[(nc + 0) * 72 + kl] = f2bf(v.x);
    tile[(nc + 1) * 72 + kl] = f2bf(v.y);
    tile[(nc + 2) * 72 + kl] = f2bf(v.z);
    tile[(nc + 3) * 72 + kl] = f2bf(v.w);
  }
  __syncthreads();
  const int nr = t >> 3;
  const int kc = (t & 7) * 8;
#pragma unroll
  for (int it = 0; it < 2; ++it) {
    int nl = it * 32 + nr;
    bf16x8 w = *(const bf16x8*)(tile + nl * 72 + kc);
    *(bf16x8*)(outp + (size_t)(n0 + nl) * K + k0 + kc) = w;
  }
}

// ------ grouped GEMM, 256x256, ring-2 + 2 blocks/CU (TLP overlap, m114 mechanism) ------
// C[e] = A[e] (CAP x K bf16 row-major) @ Bt[e]^T (Bt: N x K bf16 row-major).
// 8 waves (2M x 4N), per-wave 128x64, MFMA 16x16x32 (acc f32x4[8][4]).
// BK=32, ring-2 LDS (2 x 32KiB = 64 KiB) => 2 independent blocks/CU
// (launch_bounds(512,4); VGPR<=128). The two blocks are NOT barrier-synced
// against each other, so one block's MFMA phase overlaps the other's
// ds_read/stage phase — per-CU MFMA and LDS pipes co-run (m114).
// Per tile t (buf J=t&1): {stage(t+1)->buf J^1 | 12x ds_read(buf J) |
//   lgkmcnt(0) [mem-clobber] | sched_barrier(0) | setprio(1) 32 MFMA setprio(0) |
//   gate: vmcnt(0)+s_barrier (except last tile)}.
// vmcnt(0) gate: the only outstanding loads are stage(t+1), issued one FULL
// tile of compute earlier (~1200+ cyc > HBM latency) — drain is cheap, unlike
// the adjacent-drain m97 pathology; residue hidden by the co-resident block.
// Race-freedom: reads of buf J retire at this tile's lgkmcnt(0), before the
// gate barrier; buf J is re-staged only after the NEXT gate's barrier. RAW:
// ds_read(t+1) happens after gate(t) which retired stage(t+1). Safe.
// LDS tile layout (R1-R6, measured 0 conflicts): region [128 lds-rows][8 x 16B units];
// global (r,k): lds_row=r&127, lu=(r>>7)*4+(k>>3), phys unit=lu^(lds_row&7) (T2);
// staged via linear LDS dest + inverse-swizzled global source (rule #21).
// L2 supertiling (R6-verified: FETCH 295->197 MB): 4x4 tile supertiles per expert.
// MFMA swapped (Aop=weights bfr, Bop=tokens afr); C/D per R3 (verified):
//   acc[j][i] lane l reg r -> C[m0+wr*128+j*16+(l&15)][n0+wc*64+i*16+(l>>4)*4+r]
template <int K, int N, bool GELU_OUT>
__global__ __launch_bounds__(512, 4) void moe_gemm256_kernel(
    const u16* __restrict__ A, const u16* __restrict__ Bt,
    const float* __restrict__ bias, void* __restrict__ Out) {
  extern __shared__ __align__(16) char smem_raw[];
  constexpr int TX = N / 256;
  constexpr int NT = K / 32;
  static_assert(NT % 2 == 0 && NT >= 4, "K-tile count");
  static_assert(TX == 4 || TX == 16, "supertile map assumes TX in {4,16}");

  const int bid = blockIdx.x;
  const int e = bid & 7;          // XCD swizzle: nwg%8==0, one expert per XCD
  const int idx = bid >> 3;
  // 4x4 supertiles over the (MT=16) x TX tile grid (L2 working-set fit)
  constexpr int STC = TX / 4;     // supertile cols
  const int st = idx >> 4;        // supertile id
  const int win = idx & 15;       // position within supertile
  const int m0 = ((st / STC) * 4 + (win >> 2)) * 256;
  const int n0 = ((st % STC) * 4 + (win & 3)) * 256;

  const u16* Ae = A + (size_t)e * CAP * K;
  const u16* Be = Bt + (size_t)e * N * K;

  const int tid = threadIdx.x;
  const int l = tid & 63;
  const int w = tid >> 6;
  const int wr = w >> 2;          // 0..1 (M)
  const int wc = w & 3;           // 0..3 (N)
  const int g = l >> 4;           // 0..3 (k-unit)
  const int rl = l & 15;

  // ---- ds_read byte offsets within a buffer (swizzled, loop-invariant) ----
  int aoff[8], boff[4];
#pragma unroll
  for (int j = 0; j < 8; ++j) {
    int r = wr * 128 + j * 16 + rl;          // 0..255
    int r7 = r & 127;
    int lu = (r >> 7) * 4 + g;
    aoff[j] = r7 * 128 + ((lu ^ (r7 & 7)) << 4);
  }
#pragma unroll
  for (int i = 0; i < 4; ++i) {
    int r = wc * 64 + i * 16 + rl;           // 0..255
    int r7 = r & 127;
    int lu = (r >> 7) * 4 + g;
    boff[i] = 16384 + r7 * 128 + ((lu ^ (r7 & 7)) << 4);
  }

  // ---- staging: linear LDS dest + inverse-swizzled global source (rule #21) ----
  auto mkoff = [&](int sidx, int base0) -> size_t {
    int lrow = sidx >> 3, pu = sidx & 7;
    int lu = pu ^ (lrow & 7);
    int r = lrow + ((lu & 4) << 5);
    return (size_t)(base0 + r) * K + (lu & 3) * 8;
  };
  const u16* gA0 = Ae + mkoff(tid, m0);
  const u16* gA1 = Ae + mkoff(512 + tid, m0);
  const u16* gB0 = Be + mkoff(tid, n0);
  const u16* gB1 = Be + mkoff(512 + tid, n0);
  const int dA0 = tid * 16, dA1 = 8192 + tid * 16;
  const int dB0 = 16384 + tid * 16, dB1 = 24576 + tid * 16;

  f32x4 acc[8][4] = {};

  // ---- prologue: stage tile 0 into buf 0; gate ----
  async_ld16((const char*)gA0, smem_raw + dA0);
  async_ld16((const char*)gA1, smem_raw + dA1);
  async_ld16((const char*)gB0, smem_raw + dB0);
  async_ld16((const char*)gB1, smem_raw + dB1);
  asm volatile("s_waitcnt vmcnt(0)\n\ts_barrier" ::: "memory");
  __builtin_amdgcn_sched_barrier(0);

  // ---- one K-tile ----
  auto tileb = [&](auto JC, auto STc, auto GATEc) {
    constexpr int J = decltype(JC)::value;          // buffer / parity within group
    constexpr bool ST = decltype(STc)::value;       // stage tile t+1?
    constexpr bool GATE = decltype(GATEc)::value;   // end-of-tile gate?
    constexpr int KOFF = (J + 1) * 64;              // bytes from current group base
    const char* sr = smem_raw + J * 32768;
    char* sd = (char*)smem_raw + (J ^ 1) * 32768;
    if constexpr (ST) {
      async_ld16((const char*)gA0 + KOFF, sd + dA0);
      async_ld16((const char*)gA1 + KOFF, sd + dA1);
      async_ld16((const char*)gB0 + KOFF, sd + dB0);
      async_ld16((const char*)gB1 + KOFF, sd + dB1);
    }
    bf16x8 bfr[4], afr[8];
#pragma unroll
    for (int i = 0; i < 4; ++i) bfr[i] = *(const bf16x8*)(sr + boff[i]);
#pragma unroll
    for (int j = 0; j < 8; ++j) afr[j] = *(const bf16x8*)(sr + aoff[j]);
    // all reads of buf[J] retire here, BEFORE the gate barrier (WAR safety):
    asm volatile("s_waitcnt lgkmcnt(0)" ::: "memory");
    __builtin_amdgcn_sched_barrier(0);   // rule #18: MFMA must not hoist above wait
    __builtin_amdgcn_s_setprio(1);
#pragma unroll
    for (int j = 0; j < 8; ++j)
#pragma unroll
      for (int i = 0; i < 4; ++i)
        acc[j][i] = __builtin_amdgcn_mfma_f32_16x16x32_bf16(bfr[i], afr[j], acc[j][i], 0, 0, 0);
    __builtin_amdgcn_s_setprio(0);
    if constexpr (GATE) {
      asm volatile("s_waitcnt vmcnt(0)\n\ts_barrier" ::: "memory");
      __builtin_amdgcn_sched_barrier(0);
    }
  };

  // ---- main: groups of 2 tiles ----
#pragma unroll 1
  for (int gq = 0; gq < NT / 2 - 1; ++gq) {
    tileb(ic<0>{}, std::true_type{}, std::true_type{});
    tileb(ic<1>{}, std::true_type{}, std::true_type{});
    gA0 += 64; gA1 += 64; gB0 += 64; gB1 += 64;   // 2 tiles * 32 elems
  }
  // ---- final group: tiles NT-2, NT-1 ----
  tileb(ic<0>{}, std::true_type{}, std::true_type{});    // stages NT-1, gate retires it
  tileb(ic<1>{}, std::false_type{}, std::false_type{});  // last tile: no stage, no gate

  // ---- epilogue (R3-verified mapping) ----
  const float* be = bias + (size_t)e * N;
  const int mb = m0 + wr * 128 + rl;
  const int nb = n0 + wc * 64 + g * 4;
  if constexpr (GELU_OUT) {
    u16* Oe = (u16*)Out + (size_t)e * (size_t)CAP * N;
#pragma unroll
    for (int j = 0; j < 8; ++j) {
      int m = mb + j * 16;
#pragma unroll
      for (int i = 0; i < 4; ++i) {
        int n = nb + i * 16;
        float4 bv = *(const float4*)(be + n);
        ushort4 o;
        o.x = f2bf(gelu_f(acc[j][i][0] + bv.x));
        o.y = f2bf(gelu_f(acc[j][i][1] + bv.y));
        o.z = f2bf(gelu_f(acc[j][i][2] + bv.z));
        o.w = f2bf(gelu_f(acc[j][i][3] + bv.w));
        *(ushort4*)(Oe + (size_t)m * N + n) = o;
      }
    }
  } else {
    float* Oe = (float*)Out + (size_t)e * (size_t)CAP * N;
#pragma unroll
    for (int j = 0; j < 8; ++j) {
      int m = mb + j * 16;
#pragma unroll
      for (int i = 0; i < 4; ++i) {
        int n = nb + i * 16;
        float4 bv = *(const float4*)(be + n);
        float4 o;
        o.x = acc[j][i][0] + bv.x;
        o.y = acc[j][i][1] + bv.y;
        o.z = acc[j][i][2] + bv.z;
        o.w = acc[j][i][3] + bv.w;
        *(float4*)(Oe + (size_t)m * N + n) = o;
      }
    }
  }
}

extern "C" void kernel_launch(void* const* d_in, const int* in_sizes, int n_in,
                              void* d_out, int out_size, void* d_ws, size_t ws_size,
                              hipStream_t stream) {
  const float* x  = (const float*)d_in[0];
  // d_in[1] = expert_size (equal splits by construction; unused)
  const float* w1 = (const float*)d_in[2];
  const float* b1 = (const float*)d_in[3];
  const float* w2 = (const float*)d_in[4];
  const float* b2 = (const float*)d_in[5];
  float* out = (float*)d_out;

  char* wsp = (char*)d_ws;
  u16* x_bf = (u16*)(wsp);                             // 64 MiB
  u16* w1t  = (u16*)(wsp + (size_t)67108864);          // 64 MiB  [E][DHID][DIN]
  u16* w2t  = (u16*)(wsp + (size_t)134217728);         // 64 MiB  [E][DOUT][DHID]
  u16* h    = (u16*)(wsp + (size_t)201326592);         // 256 MiB [NTOK][DHID]

  convert_bf16_kernel<<<(NTOK * DIN) / (256 * 8), 256, 0, stream>>>(x, x_bf);
  transpose_bf16_kernel<<<dim3(DHID / 64, DIN / 64, NE), 256, 0, stream>>>(w1, w1t, DIN, DHID);
  transpose_bf16_kernel<<<dim3(DOUTD / 64, DHID / 64, NE), 256, 0, stream>>>(w2, w2t, DHID, DOUTD);

  moe_gemm256_kernel<DIN, DHID, true>
      <<<dim3(NE * (CAP / 256) * (DHID / 256)), 512, 65536, stream>>>(x_bf, w1t, b1, h);
  moe_gemm256_kernel<DHID, DOUTD, false>
      <<<dim3(NE * (CAP / 256) * (DOUTD / 256)), 512, 65536, stream>>>(h, w2t, b2, out);
}

// Round 9
// 755.789 us; speedup vs baseline: 8.0505x; 8.0505x over previous
//
#include <hip/hip_runtime.h>
#include <hip/hip_bf16.h>
#include <type_traits>

#define NE 8
#define DIN 1024
#define DHID 4096
#define DOUTD 1024
#define NTOK 32768
#define CAP (NTOK / NE)  // 4096 tokens per expert

typedef unsigned short u16;
typedef __attribute__((ext_vector_type(8))) short bf16x8;   // 8 bf16 = 4 VGPR
typedef __attribute__((ext_vector_type(4))) float f32x4;

template <int I> using ic = std::integral_constant<int, I>;

__device__ __forceinline__ u16 f2bf(float x) {
  unsigned u = __builtin_bit_cast(unsigned, x);
  u += 0x7fffu + ((u >> 16) & 1u);   // RNE; finite normals
  return (u16)(u >> 16);
}

// tanh-form GELU (max dev from erf-form ~3e-4; threshold headroom ~4.6x; R4-R6-verified)
__device__ __forceinline__ float gelu_f(float x) {
  float u = 0.7978845608028654f * x * (1.0f + 0.044715f * x * x);
  float t = __expf(-2.0f * fabsf(u));
  float r = __fdividef(2.0f * t, 1.0f + t);   // 1 - tanh|u|
  float th = copysignf(1.0f - r, u);
  return 0.5f * x * (1.0f + th);
}

__device__ __forceinline__ void async_ld16(const void* g, void* l) {
  __builtin_amdgcn_global_load_lds(
      (const __attribute__((address_space(1))) unsigned int*)g,
      (__attribute__((address_space(3))) unsigned int*)l, 16, 0, 0);
}

// ---------------- fp32 -> bf16, 8 elems/thread ----------------
__global__ __launch_bounds__(256) void convert_bf16_kernel(const float* __restrict__ in,
                                                           u16* __restrict__ out) {
  size_t i = ((size_t)blockIdx.x * 256 + threadIdx.x) * 8;
  float4 a = *(const float4*)(in + i);
  float4 b = *(const float4*)(in + i + 4);
  uint4 o;
  o.x = (unsigned)f2bf(a.x) | ((unsigned)f2bf(a.y) << 16);
  o.y = (unsigned)f2bf(a.z) | ((unsigned)f2bf(a.w) << 16);
  o.z = (unsigned)f2bf(b.x) | ((unsigned)f2bf(b.y) << 16);
  o.w = (unsigned)f2bf(b.z) | ((unsigned)f2bf(b.w) << 16);
  *(uint4*)(out + i) = o;
}

// ------------- [E][K][N] fp32 -> [E][N][K] bf16 (64x64 LDS-tiled) -------------
__global__ __launch_bounds__(256) void transpose_bf16_kernel(const float* __restrict__ in,
                                                             u16* __restrict__ out,
                                                             int K, int N) {
  __shared__ __align__(16) u16 tile[64 * 72];
  const int e = blockIdx.z;
  const int n0 = blockIdx.x * 64;
  const int k0 = blockIdx.y * 64;
  const float* inp = in + (size_t)e * K * N;
  u16* outp = out + (size_t)e * N * K;
  const int t = threadIdx.x;
  const int kr = t >> 4;
  const int nc = (t & 15) * 4;
#pragma unroll
  for (int rr = 0; rr < 4; ++rr) {
    int kl = rr * 16 + kr;
    float4 v = *(const float4*)(inp + (size_t)(k0 + kl) * N + n0 + nc);
    tile[(nc + 0) * 72 + kl] = f2bf(v.x);
    tile[(nc + 1) * 72 + kl] = f2bf(v.y);
    tile[(nc + 2) * 72 + kl] = f2bf(v.z);
    tile[(nc + 3) * 72 + kl] = f2bf(v.w);
  }
  __syncthreads();
  const int nr = t >> 3;
  const int kc = (t & 7) * 8;
#pragma unroll
  for (int it = 0; it < 2; ++it) {
    int nl = it * 32 + nr;
    bf16x8 w = *(const bf16x8*)(tile + nl * 72 + kc);
    *(bf16x8*)(outp + (size_t)(n0 + nl) * K + k0 + kc) = w;
  }
}

// ------ grouped GEMM, 256x256, ring-2 + 2 blocks/CU (TLP overlap, m114 mechanism) ------
// C[e] = A[e] (CAP x K bf16 row-major) @ Bt[e]^T (Bt: N x K bf16 row-major).
// 8 waves (2M x 4N), per-wave 128x64, MFMA 16x16x32 (acc f32x4[8][4]).
// BK=32, ring-2 LDS (2 x 32KiB = 64 KiB) => TWO blocks fit per CU by LDS
// (2x64 <= 160 KiB) and by VGPR (116 < 128, the 4-waves/SIMD step, m69).
// launch_bounds(512, 2): do NOT force 4 waves/EU on the allocator — R8 showed
// that caps regs at 128 and spills acc[8][4] to scratch (VGPR 64, 14.6 GB HBM
// scratch traffic, 8.6x regression). Residency comes from actual resources.
// The two co-resident blocks are NOT barrier-synced against each other, so one
// block's MFMA phase overlaps the other's ds_read/stage phase (m114).
// Per tile t (buf J=t&1): {stage(t+1)->buf J^1 | 12x ds_read(buf J) |
//   lgkmcnt(0) [mem-clobber] | sched_barrier(0) | setprio(1) 32 MFMA setprio(0) |
//   gate: vmcnt(0)+s_barrier (except last tile)}.
// vmcnt(0) gate: only outstanding loads are stage(t+1), issued one FULL tile
// of compute earlier (~1200+ cyc > HBM latency) — drain is cheap; residue is
// hidden by the co-resident block.
// Race-freedom: reads of buf J retire at this tile's lgkmcnt(0), before the
// gate barrier; buf J is re-staged only after the NEXT gate's barrier. RAW:
// ds_read(t+1) happens after gate(t) which retired stage(t+1). Safe.
// LDS tile layout (R1-R6, measured 0 conflicts): region [128 lds-rows][8 x 16B units];
// global (r,k): lds_row=r&127, lu=(r>>7)*4+(k>>3), phys unit=lu^(lds_row&7) (T2);
// staged via linear LDS dest + inverse-swizzled global source (rule #21).
// L2 supertiling (R6-verified: FETCH 295->197 MB): 4x4 tile supertiles per expert.
// MFMA swapped (Aop=weights bfr, Bop=tokens afr); C/D per R3 (verified):
//   acc[j][i] lane l reg r -> C[m0+wr*128+j*16+(l&15)][n0+wc*64+i*16+(l>>4)*4+r]
template <int K, int N, bool GELU_OUT>
__global__ __launch_bounds__(512, 2) void moe_gemm256_kernel(
    const u16* __restrict__ A, const u16* __restrict__ Bt,
    const float* __restrict__ bias, void* __restrict__ Out) {
  extern __shared__ __align__(16) char smem_raw[];
  constexpr int TX = N / 256;
  constexpr int NT = K / 32;
  static_assert(NT % 2 == 0 && NT >= 4, "K-tile count");
  static_assert(TX == 4 || TX == 16, "supertile map assumes TX in {4,16}");

  const int bid = blockIdx.x;
  const int e = bid & 7;          // XCD swizzle: nwg%8==0, one expert per XCD
  const int idx = bid >> 3;
  // 4x4 supertiles over the (MT=16) x TX tile grid (L2 working-set fit)
  constexpr int STC = TX / 4;     // supertile cols
  const int st = idx >> 4;        // supertile id
  const int win = idx & 15;       // position within supertile
  const int m0 = ((st / STC) * 4 + (win >> 2)) * 256;
  const int n0 = ((st % STC) * 4 + (win & 3)) * 256;

  const u16* Ae = A + (size_t)e * CAP * K;
  const u16* Be = Bt + (size_t)e * N * K;

  const int tid = threadIdx.x;
  const int l = tid & 63;
  const int w = tid >> 6;
  const int wr = w >> 2;          // 0..1 (M)
  const int wc = w & 3;           // 0..3 (N)
  const int g = l >> 4;           // 0..3 (k-unit)
  const int rl = l & 15;

  // ---- ds_read byte offsets within a buffer (swizzled, loop-invariant) ----
  int aoff[8], boff[4];
#pragma unroll
  for (int j = 0; j < 8; ++j) {
    int r = wr * 128 + j * 16 + rl;          // 0..255
    int r7 = r & 127;
    int lu = (r >> 7) * 4 + g;
    aoff[j] = r7 * 128 + ((lu ^ (r7 & 7)) << 4);
  }
#pragma unroll
  for (int i = 0; i < 4; ++i) {
    int r = wc * 64 + i * 16 + rl;           // 0..255
    int r7 = r & 127;
    int lu = (r >> 7) * 4 + g;
    boff[i] = 16384 + r7 * 128 + ((lu ^ (r7 & 7)) << 4);
  }

  // ---- staging: linear LDS dest + inverse-swizzled global source (rule #21) ----
  auto mkoff = [&](int sidx, int base0) -> size_t {
    int lrow = sidx >> 3, pu = sidx & 7;
    int lu = pu ^ (lrow & 7);
    int r = lrow + ((lu & 4) << 5);
    return (size_t)(base0 + r) * K + (lu & 3) * 8;
  };
  const u16* gA0 = Ae + mkoff(tid, m0);
  const u16* gA1 = Ae + mkoff(512 + tid, m0);
  const u16* gB0 = Be + mkoff(tid, n0);
  const u16* gB1 = Be + mkoff(512 + tid, n0);
  const int dA0 = tid * 16, dA1 = 8192 + tid * 16;
  const int dB0 = 16384 + tid * 16, dB1 = 24576 + tid * 16;

  f32x4 acc[8][4] = {};

  // ---- prologue: stage tile 0 into buf 0; gate ----
  async_ld16((const char*)gA0, smem_raw + dA0);
  async_ld16((const char*)gA1, smem_raw + dA1);
  async_ld16((const char*)gB0, smem_raw + dB0);
  async_ld16((const char*)gB1, smem_raw + dB1);
  asm volatile("s_waitcnt vmcnt(0)\n\ts_barrier" ::: "memory");
  __builtin_amdgcn_sched_barrier(0);

  // ---- one K-tile ----
  auto tileb = [&](auto JC, auto STc, auto GATEc) {
    constexpr int J = decltype(JC)::value;          // buffer / parity within group
    constexpr bool ST = decltype(STc)::value;       // stage tile t+1?
    constexpr bool GATE = decltype(GATEc)::value;   // end-of-tile gate?
    constexpr int KOFF = (J + 1) * 64;              // bytes from current group base
    const char* sr = smem_raw + J * 32768;
    char* sd = (char*)smem_raw + (J ^ 1) * 32768;
    if constexpr (ST) {
      async_ld16((const char*)gA0 + KOFF, sd + dA0);
      async_ld16((const char*)gA1 + KOFF, sd + dA1);
      async_ld16((const char*)gB0 + KOFF, sd + dB0);
      async_ld16((const char*)gB1 + KOFF, sd + dB1);
    }
    bf16x8 bfr[4], afr[8];
#pragma unroll
    for (int i = 0; i < 4; ++i) bfr[i] = *(const bf16x8*)(sr + boff[i]);
#pragma unroll
    for (int j = 0; j < 8; ++j) afr[j] = *(const bf16x8*)(sr + aoff[j]);
    // all reads of buf[J] retire here, BEFORE the gate barrier (WAR safety):
    asm volatile("s_waitcnt lgkmcnt(0)" ::: "memory");
    __builtin_amdgcn_sched_barrier(0);   // rule #18: MFMA must not hoist above wait
    __builtin_amdgcn_s_setprio(1);
#pragma unroll
    for (int j = 0; j < 8; ++j)
#pragma unroll
      for (int i = 0; i < 4; ++i)
        acc[j][i] = __builtin_amdgcn_mfma_f32_16x16x32_bf16(bfr[i], afr[j], acc[j][i], 0, 0, 0);
    __builtin_amdgcn_s_setprio(0);
    if constexpr (GATE) {
      asm volatile("s_waitcnt vmcnt(0)\n\ts_barrier" ::: "memory");
      __builtin_amdgcn_sched_barrier(0);
    }
  };

  // ---- main: groups of 2 tiles ----
#pragma unroll 1
  for (int gq = 0; gq < NT / 2 - 1; ++gq) {
    tileb(ic<0>{}, std::true_type{}, std::true_type{});
    tileb(ic<1>{}, std::true_type{}, std::true_type{});
    gA0 += 64; gA1 += 64; gB0 += 64; gB1 += 64;   // 2 tiles * 32 elems
  }
  // ---- final group: tiles NT-2, NT-1 ----
  tileb(ic<0>{}, std::true_type{}, std::true_type{});    // stages NT-1, gate retires it
  tileb(ic<1>{}, std::false_type{}, std::false_type{});  // last tile: no stage, no gate

  // ---- epilogue (R3-verified mapping) ----
  const float* be = bias + (size_t)e * N;
  const int mb = m0 + wr * 128 + rl;
  const int nb = n0 + wc * 64 + g * 4;
  if constexpr (GELU_OUT) {
    u16* Oe = (u16*)Out + (size_t)e * (size_t)CAP * N;
#pragma unroll
    for (int j = 0; j < 8; ++j) {
      int m = mb + j * 16;
#pragma unroll
      for (int i = 0; i < 4; ++i) {
        int n = nb + i * 16;
        float4 bv = *(const float4*)(be + n);
        ushort4 o;
        o.x = f2bf(gelu_f(acc[j][i][0] + bv.x));
        o.y = f2bf(gelu_f(acc[j][i][1] + bv.y));
        o.z = f2bf(gelu_f(acc[j][i][2] + bv.z));
        o.w = f2bf(gelu_f(acc[j][i][3] + bv.w));
        *(ushort4*)(Oe + (size_t)m * N + n) = o;
      }
    }
  } else {
    float* Oe = (float*)Out + (size_t)e * (size_t)CAP * N;
#pragma unroll
    for (int j = 0; j < 8; ++j) {
      int m = mb + j * 16;
#pragma unroll
      for (int i = 0; i < 4; ++i) {
        int n = nb + i * 16;
        float4 bv = *(const float4*)(be + n);
        float4 o;
        o.x = acc[j][i][0] + bv.x;
        o.y = acc[j][i][1] + bv.y;
        o.z = acc[j][i][2] + bv.z;
        o.w = acc[j][i][3] + bv.w;
        *(float4*)(Oe + (size_t)m * N + n) = o;
      }
    }
  }
}

extern "C" void kernel_launch(void* const* d_in, const int* in_sizes, int n_in,
                              void* d_out, int out_size, void* d_ws, size_t ws_size,
                              hipStream_t stream) {
  const float* x  = (const float*)d_in[0];
  // d_in[1] = expert_size (equal splits by construction; unused)
  const float* w1 = (const float*)d_in[2];
  const float* b1 = (const float*)d_in[3];
  const float* w2 = (const float*)d_in[4];
  const float* b2 = (const float*)d_in[5];
  float* out = (float*)d_out;

  char* wsp = (char*)d_ws;
  u16* x_bf = (u16*)(wsp);                             // 64 MiB
  u16* w1t  = (u16*)(wsp + (size_t)67108864);          // 64 MiB  [E][DHID][DIN]
  u16* w2t  = (u16*)(wsp + (size_t)134217728);         // 64 MiB  [E][DOUT][DHID]
  u16* h    = (u16*)(wsp + (size_t)201326592);         // 256 MiB [NTOK][DHID]

  convert_bf16_kernel<<<(NTOK * DIN) / (256 * 8), 256, 0, stream>>>(x, x_bf);
  transpose_bf16_kernel<<<dim3(DHID / 64, DIN / 64, NE), 256, 0, stream>>>(w1, w1t, DIN, DHID);
  transpose_bf16_kernel<<<dim3(DOUTD / 64, DHID / 64, NE), 256, 0, stream>>>(w2, w2t, DHID, DOUTD);

  moe_gemm256_kernel<DIN, DHID, true>
      <<<dim3(NE * (CAP / 256) * (DHID / 256)), 512, 65536, stream>>>(x_bf, w1t, b1, h);
  moe_gemm256_kernel<DHID, DOUTD, false>
      <<<dim3(NE * (CAP / 256) * (DOUTD / 256)), 512, 65536, stream>>>(h, w2t, b2, out);
}

// Round 10
// 715.161 us; speedup vs baseline: 8.5079x; 1.0568x over previous
//
#include <hip/hip_runtime.h>
#include <hip/hip_bf16.h>
#include <type_traits>

#define NE 8
#define DIN 1024
#define DHID 4096
#define DOUTD 1024
#define NTOK 32768
#define CAP (NTOK / NE)  // 4096 tokens per expert

typedef unsigned short u16;
typedef __attribute__((ext_vector_type(8))) short bf16x8;   // 8 bf16 = 4 VGPR
typedef __attribute__((ext_vector_type(4))) float f32x4;

template <int I> using ic = std::integral_constant<int, I>;

__device__ __forceinline__ u16 f2bf(float x) {
  unsigned u = __builtin_bit_cast(unsigned, x);
  u += 0x7fffu + ((u >> 16) & 1u);   // RNE; finite normals
  return (u16)(u >> 16);
}

// tanh-form GELU (max dev from erf-form ~3e-4; threshold headroom ~4.6x; R4-R9-verified)
__device__ __forceinline__ float gelu_f(float x) {
  float u = 0.7978845608028654f * x * (1.0f + 0.044715f * x * x);
  float t = __expf(-2.0f * fabsf(u));
  float r = __fdividef(2.0f * t, 1.0f + t);   // 1 - tanh|u|
  float th = copysignf(1.0f - r, u);
  return 0.5f * x * (1.0f + th);
}

__device__ __forceinline__ void async_ld16(const void* g, void* l) {
  __builtin_amdgcn_global_load_lds(
      (const __attribute__((address_space(1))) unsigned int*)g,
      (__attribute__((address_space(3))) unsigned int*)l, 16, 0, 0);
}

// ---------------- fp32 -> bf16, 8 elems/thread ----------------
__global__ __launch_bounds__(256) void convert_bf16_kernel(const float* __restrict__ in,
                                                           u16* __restrict__ out) {
  size_t i = ((size_t)blockIdx.x * 256 + threadIdx.x) * 8;
  float4 a = *(const float4*)(in + i);
  float4 b = *(const float4*)(in + i + 4);
  uint4 o;
  o.x = (unsigned)f2bf(a.x) | ((unsigned)f2bf(a.y) << 16);
  o.y = (unsigned)f2bf(a.z) | ((unsigned)f2bf(a.w) << 16);
  o.z = (unsigned)f2bf(b.x) | ((unsigned)f2bf(b.y) << 16);
  o.w = (unsigned)f2bf(b.z) | ((unsigned)f2bf(b.w) << 16);
  *(uint4*)(out + i) = o;
}

// ------------- [E][K][N] fp32 -> [E][N][K] bf16 (64x64 LDS-tiled) -------------
__global__ __launch_bounds__(256) void transpose_bf16_kernel(const float* __restrict__ in,
                                                             u16* __restrict__ out,
                                                             int K, int N) {
  __shared__ __align__(16) u16 tile[64 * 72];
  const int e = blockIdx.z;
  const int n0 = blockIdx.x * 64;
  const int k0 = blockIdx.y * 64;
  const float* inp = in + (size_t)e * K * N;
  u16* outp = out + (size_t)e * N * K;
  const int t = threadIdx.x;
  const int kr = t >> 4;
  const int nc = (t & 15) * 4;
#pragma unroll
  for (int rr = 0; rr < 4; ++rr) {
    int kl = rr * 16 + kr;
    float4 v = *(const float4*)(inp + (size_t)(k0 + kl) * N + n0 + nc);
    tile[(nc + 0) * 72 + kl] = f2bf(v.x);
    tile[(nc + 1) * 72 + kl] = f2bf(v.y);
    tile[(nc + 2) * 72 + kl] = f2bf(v.z);
    tile[(nc + 3) * 72 + kl] = f2bf(v.w);
  }
  __syncthreads();
  const int nr = t >> 3;
  const int kc = (t & 7) * 8;
#pragma unroll
  for (int it = 0; it < 2; ++it) {
    int nl = it * 32 + nr;
    bf16x8 w = *(const bf16x8*)(tile + nl * 72 + kc);
    *(bf16x8*)(outp + (size_t)(n0 + nl) * K + k0 + kc) = w;
  }
}

// -------- grouped GEMM, 256x256, BK=64, dbuf-2, FINE 4-PHASE interleave (T3+T4) --------
// C[e] = A[e] (CAP x K bf16 row-major) @ Bt[e]^T (Bt: N x K bf16 row-major).
// 8 waves (2M x 4N), per-wave 128x64, MFMA 16x16x32, acc f32x4[8][4] (128 AGPR).
// NOTE (R9 lesson): unified regs = ~104 VGPR + 128 AGPR => 2 waves/SIMD, 1 block/CU
// no matter the LDS. So optimize the INTRA-block schedule, not occupancy.
// LDS: 2 buffers x 64KB; buffer = 4 regions of 16KB: {A_kc0@0, A_kc1@16K,
// B_kc0@32K, B_kc1@48K}. Each region = proven 0-conflict layout [128 lds-rows]
// [8 x 16B units]; global (r,k in 32-chunk): lds_row=r&127, lu=(r>>7)*4+(k>>3),
// phys unit=lu^(lds_row&7) (T2); staged linear-dest + inverse-swizzled global
// source (rule #21). KEY: phase (kc,*) reads ONLY region kc => staging order
// A_kc0,B_kc0,A_kc1,B_kc1 lets gates be counted (never drain) with 2-3 phase cover.
// Per K-tile t (read buf P=t&1, stage t+1 into Q=P^1), 4 phases (kc,mh):
//  (0,0): stage A_kc0(t+1) | ds bfr_kc0[4]+afr_kc0[0-3] | barrier | lgkm0 | 16 MFMA
//  (0,1): stage B_kc0(t+1) | ds afr_kc0[4-7] | GATE vmcnt(4)+barrier | lgkm0 | 16 MFMA
//  (1,0): stage A_kc1(t+1) | ds bfr_kc1[4]+afr_kc1[0-3] | barrier | lgkm0 | 16 MFMA
//  (1,1): stage B_kc1(t+1) | ds afr_kc1[4-7] | GATE vmcnt(4)+barrier | lgkm0 | 16 MFMA
// vmcnt ledger (2 loads/phase/thread, induction verified): entering (0,0)(t):
// outstanding = kc1(t) [4]. +2 at (0,0), +2 at (0,1) => 8; GATE vmcnt(4) retires
// kc1(t) (read NEXT phase, staged 2-3 phases ago). +2+2 => 8 at (1,1); GATE
// vmcnt(4) retires kc0(t+1) (read at (0,0)(t+1), staged 2-3 phases ago). Steady
// state never drains (T4). Tail: tile NT-1 stages nothing; its (0,1) gate =
// vmcnt(0) (retires kc1(NT-1), staged during NT-2); (1,1) gate = plain barrier.
// Prologue: 8 loads of tile 0 in ledger order; vmcnt(4) retires kc0(0).
// WAR: each region's stage is >=2 barriers after that region's last reader's
// lgkm0 (readers drain pre-barrier). RAW: each region's first read is after the
// gate that retires its stage. Verified per-region (see derivation R10).
// L2 supertiling (R6: FETCH 295->197MB): 4x4 tile supertiles per expert.
// MFMA swapped (Aop=weights bfr, Bop=tokens afr); C/D per R3 (verified):
//   acc[j][i] lane l reg r -> C[m0+wr*128+j*16+(l&15)][n0+wc*64+i*16+(l>>4)*4+r]
template <int K, int N, bool GELU_OUT>
__global__ __launch_bounds__(512, 2) void moe_gemm256_kernel(
    const u16* __restrict__ A, const u16* __restrict__ Bt,
    const float* __restrict__ bias, void* __restrict__ Out) {
  extern __shared__ __align__(16) char smem_raw[];
  constexpr int TX = N / 256;
  constexpr int NT = K / 64;
  static_assert(NT % 2 == 0 && NT >= 4, "K-tile count");
  static_assert(TX == 4 || TX == 16, "supertile map assumes TX in {4,16}");

  const int bid = blockIdx.x;
  const int e = bid & 7;          // XCD swizzle: nwg%8==0, one expert per XCD
  const int idx = bid >> 3;
  constexpr int STC = TX / 4;     // supertile cols
  const int st = idx >> 4;
  const int win = idx & 15;
  const int m0 = ((st / STC) * 4 + (win >> 2)) * 256;
  const int n0 = ((st % STC) * 4 + (win & 3)) * 256;

  const u16* Ae = A + (size_t)e * CAP * K;
  const u16* Be = Bt + (size_t)e * N * K;

  const int tid = threadIdx.x;
  const int l = tid & 63;
  const int w = tid >> 6;
  const int wr = w >> 2;          // 0..1 (M)
  const int wc = w & 3;           // 0..3 (N)
  const int g = l >> 4;           // 0..3 (k-unit within 32-chunk)
  const int rl = l & 15;

  // ---- ds_read byte offsets, REGION-LOCAL (swizzled, loop-invariant) ----
  int aoff[8], boff[4];
#pragma unroll
  for (int j = 0; j < 8; ++j) {
    int r = wr * 128 + j * 16 + rl;          // 0..255
    int r7 = r & 127;
    int lu = (r >> 7) * 4 + g;
    aoff[j] = r7 * 128 + ((lu ^ (r7 & 7)) << 4);
  }
#pragma unroll
  for (int i = 0; i < 4; ++i) {
    int r = wc * 64 + i * 16 + rl;           // 0..255
    int r7 = r & 127;
    int lu = (r >> 7) * 4 + g;
    boff[i] = r7 * 128 + ((lu ^ (r7 & 7)) << 4);
  }

  // ---- staging: linear LDS dest + inverse-swizzled global source (rule #21) ----
  auto mkoff = [&](int sidx, int base0) -> size_t {
    int lrow = sidx >> 3, pu = sidx & 7;
    int lu = pu ^ (lrow & 7);
    int r = lrow + ((lu & 4) << 5);
    return (size_t)(base0 + r) * K + (lu & 3) * 8;
  };
  const u16* gA0 = Ae + mkoff(tid, m0);
  const u16* gA1 = Ae + mkoff(512 + tid, m0);
  const u16* gB0 = Be + mkoff(tid, n0);
  const u16* gB1 = Be + mkoff(512 + tid, n0);
  const int dL0 = tid * 16;          // region-local dest slot (thread)
  const int dL1 = 8192 + tid * 16;   // region-local dest slot (thread+512)

  f32x4 acc[8][4] = {};
  bf16x8 bfr[4];   // persists across the (kc,0)->(kc,1) phase pair

  // ---- one phase ----
  auto phase = [&](auto KCc, auto MHc, auto SWc, auto GNc,
                   const char* bufr, char* bufs, const int stE) {
    constexpr int KC = decltype(KCc)::value;
    constexpr int MH = decltype(MHc)::value;
    constexpr int SW = decltype(SWc)::value;     // 0=stage A, 1=stage B, 2=none
    constexpr int GN = decltype(GNc)::value;     // >=0: vmcnt(GN)+barrier; -1: plain
    if constexpr (SW == 0) {
      async_ld16(gA0 + stE + KC * 32, bufs + KC * 16384 + dL0);
      async_ld16(gA1 + stE + KC * 32, bufs + KC * 16384 + dL1);
    } else if constexpr (SW == 1) {
      async_ld16(gB0 + stE + KC * 32, bufs + 32768 + KC * 16384 + dL0);
      async_ld16(gB1 + stE + KC * 32, bufs + 32768 + KC * 16384 + dL1);
    }
    const char* ra = bufr + KC * 16384;
    const char* rb = bufr + 32768 + KC * 16384;
    bf16x8 afr[4];
    if constexpr (MH == 0) {
#pragma unroll
      for (int i = 0; i < 4; ++i) bfr[i] = *(const bf16x8*)(rb + boff[i]);
    }
#pragma unroll
    for (int j = 0; j < 4; ++j) afr[j] = *(const bf16x8*)(ra + aoff[MH * 4 + j]);
    if constexpr (GN >= 0) {
      asm volatile("s_waitcnt vmcnt(%0)\n\ts_barrier" :: "n"(GN) : "memory");
    } else {
      __builtin_amdgcn_s_barrier();
    }
    asm volatile("s_waitcnt lgkmcnt(0)" ::: "memory");
    __builtin_amdgcn_sched_barrier(0);   // rule #18
    __builtin_amdgcn_s_setprio(1);
#pragma unroll
    for (int j = 0; j < 4; ++j)
#pragma unroll
      for (int i = 0; i < 4; ++i)
        acc[MH * 4 + j][i] = __builtin_amdgcn_mfma_f32_16x16x32_bf16(
            bfr[i], afr[j], acc[MH * 4 + j][i], 0, 0, 0);
    __builtin_amdgcn_s_setprio(0);
  };

  // ---- one K-tile (J = t&1; ST: stage tile t+1; LAST: tail gates) ----
  auto tile = [&](auto Jc, auto STc, auto LASTc) {
    constexpr int J = decltype(Jc)::value;
    constexpr bool STg = decltype(STc)::value;
    constexpr bool LAST = decltype(LASTc)::value;
    const char* bufr = smem_raw + J * 65536;
    char* bufs = (char*)smem_raw + (J ^ 1) * 65536;
    constexpr int SA = STg ? 0 : 2;
    constexpr int SB = STg ? 1 : 2;
    const int stE = (J + 1) * 64;   // elems from current pair base
    phase(ic<0>{}, ic<0>{}, ic<SA>{}, ic<-1>{}, bufr, bufs, stE);
    phase(ic<0>{}, ic<1>{}, ic<SB>{}, ic<(LAST ? 0 : 4)>{}, bufr, bufs, stE);
    phase(ic<1>{}, ic<0>{}, ic<SA>{}, ic<-1>{}, bufr, bufs, stE);
    phase(ic<1>{}, ic<1>{}, ic<SB>{}, ic<(LAST ? -1 : 4)>{}, bufr, bufs, stE);
  };

  // ---- prologue: stage tile 0 in ledger order; retire kc0(0) ----
  async_ld16(gA0, smem_raw + dL0);
  async_ld16(gA1, smem_raw + dL1);
  async_ld16(gB0, smem_raw + 32768 + dL0);
  async_ld16(gB1, smem_raw + 32768 + dL1);
  async_ld16(gA0 + 32, smem_raw + 16384 + dL0);
  async_ld16(gA1 + 32, smem_raw + 16384 + dL1);
  async_ld16(gB0 + 32, smem_raw + 49152 + dL0);
  async_ld16(gB1 + 32, smem_raw + 49152 + dL1);
  asm volatile("s_waitcnt vmcnt(4)\n\ts_barrier" ::: "memory");
  __builtin_amdgcn_sched_barrier(0);

  // ---- main: pairs of tiles ----
#pragma unroll 1
  for (int pr = 0; pr < NT / 2 - 1; ++pr) {
    tile(ic<0>{}, std::true_type{}, std::false_type{});
    tile(ic<1>{}, std::true_type{}, std::false_type{});
    gA0 += 128; gA1 += 128; gB0 += 128; gB1 += 128;   // 2 tiles * 64 elems
  }
  tile(ic<0>{}, std::true_type{}, std::false_type{});   // NT-2: stages NT-1
  tile(ic<1>{}, std::false_type{}, std::true_type{});   // NT-1: tail

  // ---- epilogue (R3-verified mapping) ----
  const float* be = bias + (size_t)e * N;
  const int mb = m0 + wr * 128 + rl;
  const int nb = n0 + wc * 64 + g * 4;
  if constexpr (GELU_OUT) {
    u16* Oe = (u16*)Out + (size_t)e * (size_t)CAP * N;
#pragma unroll
    for (int j = 0; j < 8; ++j) {
      int m = mb + j * 16;
#pragma unroll
      for (int i = 0; i < 4; ++i) {
        int n = nb + i * 16;
        float4 bv = *(const float4*)(be + n);
        ushort4 o;
        o.x = f2bf(gelu_f(acc[j][i][0] + bv.x));
        o.y = f2bf(gelu_f(acc[j][i][1] + bv.y));
        o.z = f2bf(gelu_f(acc[j][i][2] + bv.z));
        o.w = f2bf(gelu_f(acc[j][i][3] + bv.w));
        *(ushort4*)(Oe + (size_t)m * N + n) = o;
      }
    }
  } else {
    float* Oe = (float*)Out + (size_t)e * (size_t)CAP * N;
#pragma unroll
    for (int j = 0; j < 8; ++j) {
      int m = mb + j * 16;
#pragma unroll
      for (int i = 0; i < 4; ++i) {
        int n = nb + i * 16;
        float4 bv = *(const float4*)(be + n);
        float4 o;
        o.x = acc[j][i][0] + bv.x;
        o.y = acc[j][i][1] + bv.y;
        o.z = acc[j][i][2] + bv.z;
        o.w = acc[j][i][3] + bv.w;
        *(float4*)(Oe + (size_t)m * N + n) = o;
      }
    }
  }
}

extern "C" void kernel_launch(void* const* d_in, const int* in_sizes, int n_in,
                              void* d_out, int out_size, void* d_ws, size_t ws_size,
                              hipStream_t stream) {
  const float* x  = (const float*)d_in[0];
  // d_in[1] = expert_size (equal splits by construction; unused)
  const float* w1 = (const float*)d_in[2];
  const float* b1 = (const float*)d_in[3];
  const float* w2 = (const float*)d_in[4];
  const float* b2 = (const float*)d_in[5];
  float* out = (float*)d_out;

  char* wsp = (char*)d_ws;
  u16* x_bf = (u16*)(wsp);                             // 64 MiB
  u16* w1t  = (u16*)(wsp + (size_t)67108864);          // 64 MiB  [E][DHID][DIN]
  u16* w2t  = (u16*)(wsp + (size_t)134217728);         // 64 MiB  [E][DOUT][DHID]
  u16* h    = (u16*)(wsp + (size_t)201326592);         // 256 MiB [NTOK][DHID]

  hipFuncSetAttribute(reinterpret_cast<const void*>(moe_gemm256_kernel<DIN, DHID, true>),
                      hipFuncAttributeMaxDynamicSharedMemorySize, 131072);
  hipFuncSetAttribute(reinterpret_cast<const void*>(moe_gemm256_kernel<DHID, DOUTD, false>),
                      hipFuncAttributeMaxDynamicSharedMemorySize, 131072);

  convert_bf16_kernel<<<(NTOK * DIN) / (256 * 8), 256, 0, stream>>>(x, x_bf);
  transpose_bf16_kernel<<<dim3(DHID / 64, DIN / 64, NE), 256, 0, stream>>>(w1, w1t, DIN, DHID);
  transpose_bf16_kernel<<<dim3(DOUTD / 64, DHID / 64, NE), 256, 0, stream>>>(w2, w2t, DHID, DOUTD);

  moe_gemm256_kernel<DIN, DHID, true>
      <<<dim3(NE * (CAP / 256) * (DHID / 256)), 512, 131072, stream>>>(x_bf, w1t, b1, h);
  moe_gemm256_kernel<DHID, DOUTD, false>
      <<<dim3(NE * (CAP / 256) * (DOUTD / 256)), 512, 131072, stream>>>(h, w2t, b2, out);
}